// Round 2
// baseline (156.984 us; speedup 1.0000x reference)
//
#include <hip/hip_runtime.h>
#include <stdint.h>

// Problem constants
#define BB 8
#define NN 1024
#define DDIM 768
#define HH 12
#define HDIM 64
#define D3 2304   // 3*D
#define MM 8192   // B*N

typedef __attribute__((ext_vector_type(4))) float f32x4;
typedef __attribute__((ext_vector_type(8))) __bf16 bf16x8;
typedef __attribute__((ext_vector_type(8))) unsigned short u16x8;
typedef __attribute__((ext_vector_type(4))) unsigned short u16x4;

__device__ __forceinline__ unsigned short f2bf(float f) {
  unsigned int u = __float_as_uint(f);
  u += 0x7FFFu + ((u >> 16) & 1u);   // RNE
  return (unsigned short)(u >> 16);
}

__device__ __forceinline__ void gload_lds16(const void* g, void* l) {
  __builtin_amdgcn_global_load_lds((const __attribute__((address_space(1))) void*)g,
                                   (__attribute__((address_space(3))) void*)l,
                                   16, 0, 0);
}

// ---------------- Kernel 1: x fp32 -> bf16 ----------------
__global__ void k_cvt_x(const float4* __restrict__ x, u16x4* __restrict__ xb, int n4) {
  int i = blockIdx.x * 256 + threadIdx.x;
  if (i >= n4) return;
  float4 v = x[i];
  u16x4 o;
  o[0] = f2bf(v.x); o[1] = f2bf(v.y); o[2] = f2bf(v.z); o[3] = f2bf(v.w);
  xb[i] = o;
}

// ---------------- Kernel 2: W [768][2304] fp32 -> Wt [2304][768] bf16 ----------------
__global__ void k_transpose_W(const float* __restrict__ W, unsigned short* __restrict__ Wt) {
  __shared__ float tile[32][33];
  const int tx = threadIdx.x & 31, ty = threadIdx.x >> 5; // ty 0..7
  const int n0 = blockIdx.x * 32;  // 72 tiles over 2304
  const int k0 = blockIdx.y * 32;  // 24 tiles over 768
  for (int i = 0; i < 4; ++i) {
    int k = k0 + ty + i * 8;
    tile[ty + i * 8][tx] = W[(size_t)k * D3 + n0 + tx];
  }
  __syncthreads();
  for (int i = 0; i < 4; ++i) {
    int n = n0 + ty + i * 8;
    Wt[(size_t)n * DDIM + k0 + tx] = f2bf(tile[tx][ty + i * 8]);
  }
}

// ---------------- Kernel 3: QKV GEMM: [8192,768]bf16 x Wt[2304,768]bf16 -> QKV bf16 [8192,2304]
__global__ __launch_bounds__(256, 2)
void k_gemm(const unsigned short* __restrict__ A, const unsigned short* __restrict__ Bt,
            const float* __restrict__ bias, unsigned short* __restrict__ C) {
  __shared__ char lds[32 * 1024];
  char* As = lds;             // [128][64] bf16, XOR-swizzled rows (16KB)
  char* Bs = lds + 16 * 1024; // [128][64] bf16 (n-major = Wt rows)
  const int t = threadIdx.x, lane = t & 63, wid = t >> 6;
  const int m0 = blockIdx.x * 128, n0 = blockIdx.y * 128;
  const int wr = wid >> 1, wc = wid & 1;
  const int grp = lane >> 4, lc = lane & 15;

  f32x4 acc[4][4];
  for (int i = 0; i < 4; ++i)
    for (int j = 0; j < 4; ++j) acc[i][j] = (f32x4)(0.0f);

  for (int kt = 0; kt < 12; ++kt) {
    // stage A-tile and B-tile (16KB each): 4 issues per wave per tile
    for (int i = 0; i < 4; ++i) {
      int id = (wid * 4 + i) * 64 + lane;      // 0..1023 chunk of 16B
      int row = id >> 3;
      int cb = (id & 7) << 4;
      int cs = cb ^ ((row & 7) << 4);          // inverse-swizzled source col
      const char* ga = (const char*)A + (size_t)(m0 + row) * (DDIM * 2) + kt * 128 + cs;
      gload_lds16(ga, As + (wid * 4 + i) * 1024);
      const char* gb = (const char*)Bt + (size_t)(n0 + row) * (DDIM * 2) + kt * 128 + cs;
      gload_lds16(gb, Bs + (wid * 4 + i) * 1024);
    }
    __syncthreads();

    bf16x8 af[4][2], bfr[4][2];
    for (int f = 0; f < 4; ++f)
      for (int kk = 0; kk < 2; ++kk) {
        int ra = wr * 64 + f * 16 + lc;
        af[f][kk] = *(const bf16x8*)(As + ra * 128 + ((kk * 64 + grp * 16) ^ ((ra & 7) << 4)));
        int rb = wc * 64 + f * 16 + lc;
        bfr[f][kk] = *(const bf16x8*)(Bs + rb * 128 + ((kk * 64 + grp * 16) ^ ((rb & 7) << 4)));
      }
    for (int mf = 0; mf < 4; ++mf)
      for (int nf = 0; nf < 4; ++nf) {
        acc[mf][nf] = __builtin_amdgcn_mfma_f32_16x16x32_bf16(af[mf][0], bfr[nf][0], acc[mf][nf], 0, 0, 0);
        acc[mf][nf] = __builtin_amdgcn_mfma_f32_16x16x32_bf16(af[mf][1], bfr[nf][1], acc[mf][nf], 0, 0, 0);
      }
    __syncthreads();
  }

  float bv[4];
  for (int nf = 0; nf < 4; ++nf) bv[nf] = bias[n0 + wc * 64 + nf * 16 + lc];
  for (int mf = 0; mf < 4; ++mf)
    for (int nf = 0; nf < 4; ++nf)
      for (int i = 0; i < 4; ++i) {
        int r = m0 + wr * 64 + mf * 16 + grp * 4 + i;
        int c = n0 + wc * 64 + nf * 16 + lc;
        C[(size_t)r * D3 + c] = f2bf(acc[mf][nf][i] + bv[nf]);
      }
}

// ---------------- Kernel 4: V slice of QKV -> Vt [96][64][1024] bf16 ----------------
__global__ void k_transpose_V(const unsigned short* __restrict__ qkv, unsigned short* __restrict__ vt) {
  __shared__ unsigned short tile[64][80];  // padded
  const int bh = blockIdx.x;       // 96
  const int nt = blockIdx.y;       // 16 tiles of 64 over N
  const int b = bh / HH, h = bh % HH;
  const int n0 = nt * 64;
  const int t = threadIdx.x;
  for (int it = 0; it < 2; ++it) {
    int id = t + it * 256;         // 0..511
    int row = id >> 3;             // n-local 0..63
    int seg = id & 7;
    const unsigned short* src = qkv + ((size_t)(b * NN + n0 + row) * D3 + 2 * DDIM + h * HDIM + seg * 8);
    *(u16x8*)&tile[row][seg * 8] = *(const u16x8*)src;
  }
  __syncthreads();
  for (int it = 0; it < 2; ++it) {
    int id = t + it * 256;
    int d = id >> 3;               // 0..63
    int seg = id & 7;              // n segment
    u16x8 o;
    for (int j = 0; j < 8; ++j) o[j] = tile[seg * 8 + j][d];
    *(u16x8*)(vt + ((size_t)bh * HDIM + d) * NN + n0 + seg * 8) = o;
  }
}

// ---------------- Kernel 5: flash attention ----------------
// grid (96, 8); 4 waves; wave w owns q-rows [w*32, w*32+32)
__global__ __launch_bounds__(256, 2)
void k_attn(const unsigned short* __restrict__ qkv, const unsigned short* __restrict__ vt,
            float* __restrict__ out) {
  __shared__ char lds[48 * 1024];
  char* Qs = lds;                // [128][64] bf16 swizzled, 16KB
  char* Ks = lds + 16 * 1024;    // [64][64]  8KB
  char* Vs = lds + 24 * 1024;    // [64][64]  (rows = d) 8KB
  char* Ps = lds + 32 * 1024;    // [128][64] bf16 swizzled, 16KB (wave-private rows)
  const int t = threadIdx.x, lane = t & 63, wid = t >> 6;
  const int bh = blockIdx.x, qt = blockIdx.y;
  const int b = bh / HH, h = bh % HH;
  const int q0 = qt * 128;
  const int grp = lane >> 4, lc = lane & 15;
  const float SCL = 0.125f * 1.44269504089f;  // 1/sqrt(64) * log2(e)

  // stage Q tile (16KB)
  for (int i = 0; i < 4; ++i) {
    int id = (wid * 4 + i) * 64 + lane;
    int row = id >> 3;
    int cb = (id & 7) << 4;
    int cs = cb ^ ((row & 7) << 4);
    const char* g = (const char*)qkv + ((size_t)(b * NN + q0 + row) * D3 + h * HDIM) * 2 + cs;
    gload_lds16(g, Qs + (wid * 4 + i) * 1024);
  }
  __syncthreads();

  bf16x8 qa[2][2];
  for (int qf = 0; qf < 2; ++qf)
    for (int kk = 0; kk < 2; ++kk) {
      int row = wid * 32 + qf * 16 + lc;
      qa[qf][kk] = *(const bf16x8*)(Qs + row * 128 + ((kk * 64 + grp * 16) ^ ((row & 7) << 4)));
    }

  f32x4 acc[2][4];
  for (int i = 0; i < 2; ++i)
    for (int j = 0; j < 4; ++j) acc[i][j] = (f32x4)(0.0f);
  float mrow[2][4], lrow[2][4];
  for (int i = 0; i < 2; ++i)
    for (int j = 0; j < 4; ++j) { mrow[i][j] = -1e30f; lrow[i][j] = 0.0f; }

  for (int kt = 0; kt < 16; ++kt) {
    const int kb = kt * 64;
    // stage K tile and Vt tile (8KB each): 2 issues/wave each
    for (int i = 0; i < 2; ++i) {
      int id = (wid * 2 + i) * 64 + lane;   // 0..511
      int row = id >> 3;
      int cb = (id & 7) << 4;
      int cs = cb ^ ((row & 7) << 4);
      const char* gk = (const char*)qkv + ((size_t)(b * NN + kb + row) * D3 + DDIM + h * HDIM) * 2 + cs;
      gload_lds16(gk, Ks + (wid * 2 + i) * 1024);
      const char* gv = (const char*)vt + ((size_t)(bh * HDIM + row) * NN + kb) * 2 + cs;
      gload_lds16(gv, Vs + (wid * 2 + i) * 1024);
    }
    __syncthreads();

    // S = Q K^T  (raw, scale folded into exp2)
    bf16x8 kbf[4][2];
    for (int kf = 0; kf < 4; ++kf)
      for (int kk = 0; kk < 2; ++kk) {
        int row = kf * 16 + lc;
        kbf[kf][kk] = *(const bf16x8*)(Ks + row * 128 + ((kk * 64 + grp * 16) ^ ((row & 7) << 4)));
      }
    f32x4 s[2][4];
    for (int qf = 0; qf < 2; ++qf)
      for (int kf = 0; kf < 4; ++kf) {
        s[qf][kf] = (f32x4)(0.0f);
        s[qf][kf] = __builtin_amdgcn_mfma_f32_16x16x32_bf16(qa[qf][0], kbf[kf][0], s[qf][kf], 0, 0, 0);
        s[qf][kf] = __builtin_amdgcn_mfma_f32_16x16x32_bf16(qa[qf][1], kbf[kf][1], s[qf][kf], 0, 0, 0);
      }

    // online softmax (rows live across 16 lanes: shfl_xor over low 4 bits)
    for (int qf = 0; qf < 2; ++qf) {
      float tmax[4], rs[4];
      for (int i = 0; i < 4; ++i)
        tmax[i] = fmaxf(fmaxf(s[qf][0][i], s[qf][1][i]), fmaxf(s[qf][2][i], s[qf][3][i]));
      for (int m = 1; m <= 8; m <<= 1)
        for (int i = 0; i < 4; ++i) tmax[i] = fmaxf(tmax[i], __shfl_xor(tmax[i], m, 64));
      for (int i = 0; i < 4; ++i) {
        float mnew = fmaxf(mrow[qf][i], tmax[i]);
        float rf = exp2f((mrow[qf][i] - mnew) * SCL);
        mrow[qf][i] = mnew;
        float r = 0.0f;
        for (int kf = 0; kf < 4; ++kf) {
          float p = exp2f((s[qf][kf][i] - mnew) * SCL);
          s[qf][kf][i] = p;
          r += p;
        }
        rs[i] = r;
        for (int df = 0; df < 4; ++df) acc[qf][df][i] *= rf;
        lrow[qf][i] *= rf;
      }
      for (int m = 1; m <= 8; m <<= 1)
        for (int i = 0; i < 4; ++i) rs[i] += __shfl_xor(rs[i], m, 64);
      for (int i = 0; i < 4; ++i) lrow[qf][i] += rs[i];
    }

    // P -> bf16 -> wave-private LDS rows (swizzled), then re-read as A-fragments
    for (int qf = 0; qf < 2; ++qf)
      for (int kf = 0; kf < 4; ++kf)
        for (int i = 0; i < 4; ++i) {
          int row = wid * 32 + qf * 16 + grp * 4 + i;
          int col = kf * 16 + lc;
          *(unsigned short*)(Ps + row * 128 + ((col * 2) ^ ((row & 7) << 4))) = f2bf(s[qf][kf][i]);
        }

    bf16x8 vb[4][2], pa[2][2];
    for (int df = 0; df < 4; ++df)
      for (int kk = 0; kk < 2; ++kk) {
        int row = df * 16 + lc;  // d row
        vb[df][kk] = *(const bf16x8*)(Vs + row * 128 + ((kk * 64 + grp * 16) ^ ((row & 7) << 4)));
      }
    for (int qf = 0; qf < 2; ++qf)
      for (int kk = 0; kk < 2; ++kk) {
        int row = wid * 32 + qf * 16 + lc;
        pa[qf][kk] = *(const bf16x8*)(Ps + row * 128 + ((kk * 64 + grp * 16) ^ ((row & 7) << 4)));
      }
    for (int qf = 0; qf < 2; ++qf)
      for (int df = 0; df < 4; ++df) {
        acc[qf][df] = __builtin_amdgcn_mfma_f32_16x16x32_bf16(pa[qf][0], vb[df][0], acc[qf][df], 0, 0, 0);
        acc[qf][df] = __builtin_amdgcn_mfma_f32_16x16x32_bf16(pa[qf][1], vb[df][1], acc[qf][df], 0, 0, 0);
      }
    __syncthreads();  // protect Ks/Vs before next stage
  }

  // epilogue: divide by denominator, store fp32
  for (int qf = 0; qf < 2; ++qf)
    for (int df = 0; df < 4; ++df)
      for (int i = 0; i < 4; ++i) {
        int q = q0 + wid * 32 + qf * 16 + grp * 4 + i;
        int dcol = h * HDIM + df * 16 + lc;
        out[((size_t)b * NN + q) * DDIM + dcol] = acc[qf][df][i] / lrow[qf][i];
      }
}

// ---------------- launch ----------------
extern "C" void kernel_launch(void* const* d_in, const int* in_sizes, int n_in,
                              void* d_out, int out_size, void* d_ws, size_t ws_size,
                              hipStream_t stream) {
  const float* x = (const float*)d_in[0];
  const float* W = (const float*)d_in[1];
  const float* bqkv = (const float*)d_in[2];
  float* out = (float*)d_out;
  char* ws = (char*)d_ws;

  // workspace layout (bytes)
  const size_t XB_OFF = 0;                       // 8192*768*2   = 12,582,912
  const size_t WT_OFF = 12582912;                // 2304*768*2   =  3,538,944
  const size_t QKV_OFF = WT_OFF + 3538944;       // 8192*2304*2  = 37,748,736
  const size_t VT_OFF = QKV_OFF + 37748736;      // 96*64*1024*2 = 12,582,912
  unsigned short* xb = (unsigned short*)(ws + XB_OFF);
  unsigned short* wt = (unsigned short*)(ws + WT_OFF);
  unsigned short* qkvb = (unsigned short*)(ws + QKV_OFF);
  unsigned short* vtb = (unsigned short*)(ws + VT_OFF);

  const int n4 = (MM * DDIM) / 4;  // 1,572,864
  k_cvt_x<<<dim3((n4 + 255) / 256), dim3(256), 0, stream>>>((const float4*)x, (u16x4*)xb, n4);
  k_transpose_W<<<dim3(D3 / 32, DDIM / 32), dim3(256), 0, stream>>>(W, wt);
  k_gemm<<<dim3(MM / 128, D3 / 128), dim3(256), 0, stream>>>(xb, wt, bqkv, qkvb);
  k_transpose_V<<<dim3(BB * HH, NN / 64), dim3(256), 0, stream>>>(qkvb, vtb);
  k_attn<<<dim3(BB * HH, NN / 128), dim3(256), 0, stream>>>(qkvb, vtb, out);
}

// Round 3
// 114.621 us; speedup vs baseline: 1.3696x; 1.3696x over previous
//
#include <hip/hip_runtime.h>
#include <stdint.h>

// Problem constants
#define BB 8
#define NN 1024
#define DDIM 768
#define HH 12
#define HDIM 64
#define D3 2304   // 3*D
#define MM 8192   // B*N

typedef __attribute__((ext_vector_type(4))) float f32x4;
typedef __attribute__((ext_vector_type(16))) float f32x16;
typedef __attribute__((ext_vector_type(8))) __bf16 bf16x8;
typedef __attribute__((ext_vector_type(8))) unsigned short u16x8;
typedef __attribute__((ext_vector_type(4))) unsigned short u16x4;

__device__ __forceinline__ unsigned short f2bf(float f) {
  unsigned int u = __float_as_uint(f);
  u += 0x7FFFu + ((u >> 16) & 1u);   // RNE
  return (unsigned short)(u >> 16);
}

__device__ __forceinline__ void gload_lds16(const void* g, void* l) {
  __builtin_amdgcn_global_load_lds((const __attribute__((address_space(1))) void*)g,
                                   (__attribute__((address_space(3))) void*)l,
                                   16, 0, 0);
}

__device__ __forceinline__ unsigned cvtpk_bf16(float lo, float hi) {
  unsigned r;
  asm("v_cvt_pk_bf16_f32 %0, %1, %2" : "=v"(r) : "v"(lo), "v"(hi));
  return r;
}

__device__ __forceinline__ bf16x8 mkfrag(unsigned a, unsigned b, unsigned c, unsigned d) {
  union { unsigned u[4]; bf16x8 v; } x;
  x.u[0] = a; x.u[1] = b; x.u[2] = c; x.u[3] = d;
  return x.v;
}

// ---------------- Kernel 1: x fp32 -> bf16 ----------------
__global__ void k_cvt_x(const float4* __restrict__ x, u16x4* __restrict__ xb, int n4) {
  int i = blockIdx.x * 256 + threadIdx.x;
  if (i >= n4) return;
  float4 v = x[i];
  u16x4 o;
  o[0] = f2bf(v.x); o[1] = f2bf(v.y); o[2] = f2bf(v.z); o[3] = f2bf(v.w);
  xb[i] = o;
}

// ---------------- Kernel 2: W [768][2304] fp32 -> Wt [2304][768] bf16 ----------------
__global__ void k_transpose_W(const float* __restrict__ W, unsigned short* __restrict__ Wt) {
  __shared__ float tile[32][33];
  const int tx = threadIdx.x & 31, ty = threadIdx.x >> 5; // ty 0..7
  const int n0 = blockIdx.x * 32;
  const int k0 = blockIdx.y * 32;
  for (int i = 0; i < 4; ++i) {
    int k = k0 + ty + i * 8;
    tile[ty + i * 8][tx] = W[(size_t)k * D3 + n0 + tx];
  }
  __syncthreads();
  for (int i = 0; i < 4; ++i) {
    int n = n0 + ty + i * 8;
    Wt[(size_t)n * DDIM + k0 + tx] = f2bf(tile[tx][ty + i * 8]);
  }
}

// ---------------- Kernel 3: QKV GEMM ----------------
__global__ __launch_bounds__(256, 2)
void k_gemm(const unsigned short* __restrict__ A, const unsigned short* __restrict__ Bt,
            const float* __restrict__ bias, unsigned short* __restrict__ C) {
  __shared__ char lds[32 * 1024];
  char* As = lds;
  char* Bs = lds + 16 * 1024;
  const int t = threadIdx.x, lane = t & 63, wid = t >> 6;
  // bijective XCD swizzle: 1152 = 8 * 144
  const int orig = blockIdx.x;
  const int wg = (orig & 7) * 144 + (orig >> 3);
  const int m0 = (wg & 63) * 128, n0 = (wg >> 6) * 128;
  const int wr = wid >> 1, wc = wid & 1;
  const int grp = lane >> 4, lc = lane & 15;

  f32x4 acc[4][4];
  for (int i = 0; i < 4; ++i)
    for (int j = 0; j < 4; ++j) acc[i][j] = (f32x4)(0.0f);

  for (int kt = 0; kt < 12; ++kt) {
    for (int i = 0; i < 4; ++i) {
      int id = (wid * 4 + i) * 64 + lane;
      int row = id >> 3;
      int cb = (id & 7) << 4;
      int cs = cb ^ ((row & 7) << 4);
      const char* ga = (const char*)A + (size_t)(m0 + row) * (DDIM * 2) + kt * 128 + cs;
      gload_lds16(ga, As + (wid * 4 + i) * 1024);
      const char* gb = (const char*)Bt + (size_t)(n0 + row) * (DDIM * 2) + kt * 128 + cs;
      gload_lds16(gb, Bs + (wid * 4 + i) * 1024);
    }
    __syncthreads();

    bf16x8 af[4][2], bfr[4][2];
    for (int f = 0; f < 4; ++f)
      for (int kk = 0; kk < 2; ++kk) {
        int ra = wr * 64 + f * 16 + lc;
        af[f][kk] = *(const bf16x8*)(As + ra * 128 + ((kk * 64 + grp * 16) ^ ((ra & 7) << 4)));
        int rb = wc * 64 + f * 16 + lc;
        bfr[f][kk] = *(const bf16x8*)(Bs + rb * 128 + ((kk * 64 + grp * 16) ^ ((rb & 7) << 4)));
      }
    for (int mf = 0; mf < 4; ++mf)
      for (int nf = 0; nf < 4; ++nf) {
        acc[mf][nf] = __builtin_amdgcn_mfma_f32_16x16x32_bf16(af[mf][0], bfr[nf][0], acc[mf][nf], 0, 0, 0);
        acc[mf][nf] = __builtin_amdgcn_mfma_f32_16x16x32_bf16(af[mf][1], bfr[nf][1], acc[mf][nf], 0, 0, 0);
      }
    __syncthreads();
  }

  float bv[4];
  for (int nf = 0; nf < 4; ++nf) bv[nf] = bias[n0 + wc * 64 + nf * 16 + lc];
  for (int mf = 0; mf < 4; ++mf)
    for (int nf = 0; nf < 4; ++nf)
      for (int i = 0; i < 4; ++i) {
        int r = m0 + wr * 64 + mf * 16 + grp * 4 + i;
        int c = n0 + wc * 64 + nf * 16 + lc;
        C[(size_t)r * D3 + c] = f2bf(acc[mf][nf][i] + bv[nf]);
      }
}

// ---------------- Kernel 4: V slice of QKV -> Vt [96][64][1024] bf16 ----------------
__global__ void k_transpose_V(const unsigned short* __restrict__ qkv, unsigned short* __restrict__ vt) {
  __shared__ unsigned short tile[64][80];
  const int bh = blockIdx.x;
  const int nt = blockIdx.y;
  const int b = bh / HH, h = bh % HH;
  const int n0 = nt * 64;
  const int t = threadIdx.x;
  for (int it = 0; it < 2; ++it) {
    int id = t + it * 256;
    int row = id >> 3;
    int seg = id & 7;
    const unsigned short* src = qkv + ((size_t)(b * NN + n0 + row) * D3 + 2 * DDIM + h * HDIM + seg * 8);
    *(u16x8*)&tile[row][seg * 8] = *(const u16x8*)src;
  }
  __syncthreads();
  for (int it = 0; it < 2; ++it) {
    int id = t + it * 256;
    int d = id >> 3;
    int seg = id & 7;
    u16x8 o;
    for (int j = 0; j < 8; ++j) o[j] = tile[seg * 8 + j][d];
    *(u16x8*)(vt + ((size_t)bh * HDIM + d) * NN + n0 + seg * 8) = o;
  }
}

// ---------------- Kernel 5: flash attention (swapped 32x32 MFMA) ----------------
// 1D grid 768 (XCD-swizzled); 4 waves; wave w owns q rows [qt*128 + w*32, +32)
__global__ __launch_bounds__(256, 3)
void k_attn(const unsigned short* __restrict__ qkv, const unsigned short* __restrict__ vt,
            float* __restrict__ out) {
  __shared__ char lds[32 * 1024];   // Ks[2][64][64]bf16 | Vs[2][64][64]bf16
  const int t = threadIdx.x, lane = t & 63, wid = t >> 6;
  // bijective XCD swizzle: 768 = 8 * 96; groups all 8 q-tiles of a head per XCD
  const int orig = blockIdx.x;
  const int wg = (orig & 7) * 96 + (orig >> 3);
  const int bh = wg >> 3, qt = wg & 7;
  const int b = bh / HH, h = bh % HH;
  const int q0 = qt * 128 + wid * 32;
  const int l31 = lane & 31, hi = lane >> 5;
  const float SCL = 0.125f * 1.44269504089f;  // 1/sqrt(64) * log2(e)

  // ---- Q B-fragments direct from global: B[k=d][n=q], lane: col q=l31, k=hi*8+j ----
  bf16x8 qf[4];
  const char* qbase = (const char*)qkv + ((size_t)(b * NN + q0 + l31) * D3 + h * HDIM) * 2;
#pragma unroll
  for (int ds_ = 0; ds_ < 4; ++ds_)
    qf[ds_] = *(const bf16x8*)(qbase + ds_ * 32 + hi * 16);

  f32x16 acc0 = (f32x16)(0.0f), acc1 = (f32x16)(0.0f);
  float m = -1e30f, l = 0.0f;

  // ---- staging: K tile + Vt tile, 8KB each, linear LDS dest + inverse-swizzled src ----
  auto STAGE = [&](int bi, int kb) {
#pragma unroll
    for (int i = 0; i < 2; ++i) {
      int chunk = wid * 2 + i;                // 0..7 (8 rows each)
      int row = chunk * 8 + (lane >> 3);
      int cs = ((lane & 7) << 4) ^ ((row & 7) << 4);
      const char* gk = (const char*)qkv + ((size_t)(b * NN + kb + row) * D3 + DDIM + h * HDIM) * 2 + cs;
      gload_lds16(gk, lds + bi * 8192 + chunk * 1024);
      const char* gv = (const char*)vt + ((size_t)(bh * HDIM + row) * NN + kb) * 2 + cs;
      gload_lds16(gv, lds + 16384 + bi * 8192 + chunk * 1024);
    }
  };

  STAGE(0, 0);
  __syncthreads();

  for (int kt = 0; kt < 16; ++kt) {
    const int cur = kt & 1;
    if (kt < 15) STAGE(cur ^ 1, (kt + 1) * 64);
    const char* Kc = lds + cur * 8192;
    const char* Vc = lds + 16384 + cur * 8192;

    // ---- S^T = K . Q^T : lane holds q=l31, k-halves per hi ----
    f32x16 st0 = (f32x16)(0.0f), st1 = (f32x16)(0.0f);
    __builtin_amdgcn_s_setprio(1);
#pragma unroll
    for (int ds_ = 0; ds_ < 4; ++ds_) {
      const int co = ds_ * 32 + hi * 16;
      const int r0 = l31, r1 = 32 + l31;
      bf16x8 k0 = *(const bf16x8*)(Kc + r0 * 128 + (co ^ ((r0 & 7) << 4)));
      bf16x8 k1 = *(const bf16x8*)(Kc + r1 * 128 + (co ^ ((r1 & 7) << 4)));
      st0 = __builtin_amdgcn_mfma_f32_32x32x16_bf16(k0, qf[ds_], st0, 0, 0, 0);
      st1 = __builtin_amdgcn_mfma_f32_32x32x16_bf16(k1, qf[ds_], st1, 0, 0, 0);
    }
    __builtin_amdgcn_s_setprio(0);

    // ---- online softmax, lane-local rows + one cross-half shfl ----
    float t0 = st0[0], t1 = st0[1], t2 = st0[2], t3 = st0[3];
#pragma unroll
    for (int i = 4; i < 16; i += 4) {
      t0 = fmaxf(t0, st0[i]); t1 = fmaxf(t1, st0[i + 1]);
      t2 = fmaxf(t2, st0[i + 2]); t3 = fmaxf(t3, st0[i + 3]);
    }
#pragma unroll
    for (int i = 0; i < 16; i += 4) {
      t0 = fmaxf(t0, st1[i]); t1 = fmaxf(t1, st1[i + 1]);
      t2 = fmaxf(t2, st1[i + 2]); t3 = fmaxf(t3, st1[i + 3]);
    }
    float tm = fmaxf(fmaxf(t0, t1), fmaxf(t2, t3)) * SCL;
    tm = fmaxf(tm, __shfl_xor(tm, 32, 64));

    // defer-max (T13): rescale only when tile max exceeds m by > 8 (log2 domain)
    if (!__all(tm <= m + 8.0f)) {
      float mn = fmaxf(m, tm);
      float rf = exp2f(m - mn);
      m = mn; l *= rf;
#pragma unroll
      for (int i = 0; i < 16; ++i) { acc0[i] *= rf; acc1[i] *= rf; }
    }

    float s0 = 0.f, s1 = 0.f, s2 = 0.f, s3 = 0.f;
#pragma unroll
    for (int i = 0; i < 16; i += 4) {
      float p0 = exp2f(fmaf(st0[i], SCL, -m));
      float p1 = exp2f(fmaf(st0[i + 1], SCL, -m));
      float p2 = exp2f(fmaf(st0[i + 2], SCL, -m));
      float p3 = exp2f(fmaf(st0[i + 3], SCL, -m));
      st0[i] = p0; st0[i + 1] = p1; st0[i + 2] = p2; st0[i + 3] = p3;
      s0 += p0; s1 += p1; s2 += p2; s3 += p3;
    }
#pragma unroll
    for (int i = 0; i < 16; i += 4) {
      float p0 = exp2f(fmaf(st1[i], SCL, -m));
      float p1 = exp2f(fmaf(st1[i + 1], SCL, -m));
      float p2 = exp2f(fmaf(st1[i + 2], SCL, -m));
      float p3 = exp2f(fmaf(st1[i + 3], SCL, -m));
      st1[i] = p0; st1[i + 1] = p1; st1[i + 2] = p2; st1[i + 3] = p3;
      s0 += p0; s1 += p1; s2 += p2; s3 += p3;
    }
    l += (s0 + s1) + (s2 + s3);

    // ---- P -> bf16 fragments in-register (cross-half exchange via shfl_xor 32) ----
    // per kblk: own pairs c0..c7 (k pairs ascending); frag words need own/partner mix
#pragma unroll
    for (int kblk = 0; kblk < 2; ++kblk) {
      const f32x16& sp = kblk ? st1 : st0;
      unsigned c0 = cvtpk_bf16(sp[0], sp[1]),   c1 = cvtpk_bf16(sp[2], sp[3]);
      unsigned c2 = cvtpk_bf16(sp[4], sp[5]),   c3 = cvtpk_bf16(sp[6], sp[7]);
      unsigned c4 = cvtpk_bf16(sp[8], sp[9]),   c5 = cvtpk_bf16(sp[10], sp[11]);
      unsigned c6 = cvtpk_bf16(sp[12], sp[13]), c7 = cvtpk_bf16(sp[14], sp[15]);
      unsigned x0 = __shfl_xor(c0, 32, 64), x1 = __shfl_xor(c1, 32, 64);
      unsigned x2 = __shfl_xor(c2, 32, 64), x3 = __shfl_xor(c3, 32, 64);
      unsigned x4 = __shfl_xor(c4, 32, 64), x5 = __shfl_xor(c5, 32, 64);
      unsigned x6 = __shfl_xor(c6, 32, 64), x7 = __shfl_xor(c7, 32, 64);
      // chunk0 (tile k [kblk*32, kblk*32+16)): lane hi needs k = 8hi+j
      bf16x8 pf0 = mkfrag(hi ? x2 : c0, hi ? x3 : c1, hi ? c2 : x0, hi ? c3 : x1);
      // chunk1 (k [kblk*32+16, kblk*32+32))
      bf16x8 pf1 = mkfrag(hi ? x6 : c4, hi ? x7 : c5, hi ? c6 : x4, hi ? c7 : x5);

      __builtin_amdgcn_s_setprio(1);
#pragma unroll
      for (int ch = 0; ch < 2; ++ch) {
        const int co = (kblk * 2 + ch) * 32 + hi * 16;
        const int r0 = l31, r1 = 32 + l31;
        bf16x8 v0 = *(const bf16x8*)(Vc + r0 * 128 + (co ^ ((r0 & 7) << 4)));
        bf16x8 v1 = *(const bf16x8*)(Vc + r1 * 128 + (co ^ ((r1 & 7) << 4)));
        const bf16x8 pf = ch ? pf1 : pf0;
        acc0 = __builtin_amdgcn_mfma_f32_32x32x16_bf16(v0, pf, acc0, 0, 0, 0);
        acc1 = __builtin_amdgcn_mfma_f32_32x32x16_bf16(v1, pf, acc1, 0, 0, 0);
      }
      __builtin_amdgcn_s_setprio(0);
    }

    __syncthreads();
  }

  // ---- epilogue: combine halves of l, divide, store O^T (f32x4 per reg-quad) ----
  float lf = l + __shfl_xor(l, 32, 64);
  float inv = 1.0f / lf;
  float* obase = out + (size_t)(b * NN + q0 + l31) * DDIM + h * HDIM + hi * 4;
#pragma unroll
  for (int rq = 0; rq < 4; ++rq) {
    f32x4 o;
    o[0] = acc0[rq * 4] * inv; o[1] = acc0[rq * 4 + 1] * inv;
    o[2] = acc0[rq * 4 + 2] * inv; o[3] = acc0[rq * 4 + 3] * inv;
    *(f32x4*)(obase + rq * 8) = o;
  }
#pragma unroll
  for (int rq = 0; rq < 4; ++rq) {
    f32x4 o;
    o[0] = acc1[rq * 4] * inv; o[1] = acc1[rq * 4 + 1] * inv;
    o[2] = acc1[rq * 4 + 2] * inv; o[3] = acc1[rq * 4 + 3] * inv;
    *(f32x4*)(obase + 32 + rq * 8) = o;
  }
}

// ---------------- launch ----------------
extern "C" void kernel_launch(void* const* d_in, const int* in_sizes, int n_in,
                              void* d_out, int out_size, void* d_ws, size_t ws_size,
                              hipStream_t stream) {
  const float* x = (const float*)d_in[0];
  const float* W = (const float*)d_in[1];
  const float* bqkv = (const float*)d_in[2];
  float* out = (float*)d_out;
  char* ws = (char*)d_ws;

  const size_t XB_OFF = 0;                       // 8192*768*2
  const size_t WT_OFF = 12582912;                // 2304*768*2
  const size_t QKV_OFF = WT_OFF + 3538944;       // 8192*2304*2
  const size_t VT_OFF = QKV_OFF + 37748736;      // 96*64*1024*2
  unsigned short* xb = (unsigned short*)(ws + XB_OFF);
  unsigned short* wt = (unsigned short*)(ws + WT_OFF);
  unsigned short* qkvb = (unsigned short*)(ws + QKV_OFF);
  unsigned short* vtb = (unsigned short*)(ws + VT_OFF);

  const int n4 = (MM * DDIM) / 4;
  k_cvt_x<<<dim3((n4 + 255) / 256), dim3(256), 0, stream>>>((const float4*)x, (u16x4*)xb, n4);
  k_transpose_W<<<dim3(D3 / 32, DDIM / 32), dim3(256), 0, stream>>>(W, wt);
  k_gemm<<<dim3(1152), dim3(256), 0, stream>>>(xb, wt, bqkv, qkvb);
  k_transpose_V<<<dim3(BB * HH, NN / 64), dim3(256), 0, stream>>>(qkvb, vtb);
  k_attn<<<dim3(768), dim3(256), 0, stream>>>(qkvb, vtb, out);
}